// Round 5
// baseline (2779.595 us; speedup 1.0000x reference)
//
#include <hip/hip_runtime.h>

#define N_NODES 20000
#define N_EDGES 320000
#define SEQ 8
#define GRID_MAIN 512           // 2 blocks/CU on 256 CUs -- guaranteed resident
#define WAVES_MAIN (GRID_MAIN * 4)

typedef __attribute__((ext_vector_type(8))) short bf16x8;
typedef __attribute__((ext_vector_type(4))) float floatx4;

__device__ __forceinline__ unsigned short f2bf(float f) {
  unsigned int u = __builtin_bit_cast(unsigned int, f);
  return (unsigned short)((u + 0x7fffu + ((u >> 16) & 1u)) >> 16);
}
__device__ __forceinline__ float bflo(unsigned int u) {
  return __builtin_bit_cast(float, u << 16);
}
__device__ __forceinline__ float bfhi(unsigned int u) {
  return __builtin_bit_cast(float, u & 0xffff0000u);
}
__device__ __forceinline__ float sigf(float x) { return 1.f / (1.f + __expf(-x)); }

// Device-scope grid barrier (sense-generation). All blocks resident by
// construction (512 blocks, 2/CU via __launch_bounds__(256,2), 36KB LDS).
// bar/gen live in d_ws, zeroed by k_prologue each call.
__device__ __forceinline__ void gsync(int* bar, int* gen, int& lgen) {
  ++lgen;
  __syncthreads();
  if (threadIdx.x == 0) {
    __threadfence();  // flush this block's writes device-wide
    int ticket = __hip_atomic_fetch_add(bar, 1, __ATOMIC_ACQ_REL,
                                        __HIP_MEMORY_SCOPE_AGENT);
    if (ticket == GRID_MAIN - 1) {
      __hip_atomic_store(bar, 0, __ATOMIC_RELAXED, __HIP_MEMORY_SCOPE_AGENT);
      __hip_atomic_fetch_add(gen, 1, __ATOMIC_RELEASE,
                             __HIP_MEMORY_SCOPE_AGENT);
    } else {
      while (__hip_atomic_load(gen, __ATOMIC_ACQUIRE,
                               __HIP_MEMORY_SCOPE_AGENT) < lgen)
        __builtin_amdgcn_s_sleep(2);
    }
    __threadfence();  // acquire: invalidate stale cached lines
  }
  __syncthreads();
}

// ---------------- setup kernels ----------------

__global__ void k_prologue(const float* __restrict__ Wi,
                           const float* __restrict__ Wc,
                           unsigned short* __restrict__ WiT,
                           unsigned short* __restrict__ WcT,
                           float* __restrict__ deg, int* __restrict__ counts,
                           int* __restrict__ bar, int* __restrict__ gen) {
  int idx = blockIdx.x * 256 + threadIdx.x;  // 0..131071
  if (idx == 0) { bar[0] = 0; gen[0] = 0; }
  if (idx < N_NODES) { deg[idx] = 1.0f; counts[idx] = 0; }
  if (idx < 65536) {
    int n = idx >> 8, k = idx & 255;
    WiT[n * 256 + k] = f2bf(Wi[k * 256 + n]);
  }
  int n2 = idx >> 8, k = idx & 255;  // n2 0..511, gate-interleaved
  int orig = ((n2 & 3) << 7) | (n2 >> 2);
  WcT[n2 * 256 + k] = f2bf(Wc[k * 512 + orig]);
}

__global__ void k_deg(const int* __restrict__ ei, const float* __restrict__ ea,
                      float* __restrict__ deg, int* __restrict__ counts) {
  int e = blockIdx.x * 256 + threadIdx.x;
  if (e >= N_EDGES) return;
  int d = ei[N_EDGES + e];
  atomicAdd(&deg[d], ea[e]);
  atomicAdd(&counts[d], 1);
}

__global__ void k_scan1(const int* __restrict__ counts, int* __restrict__ incl,
                        int* __restrict__ part, const float* __restrict__ deg,
                        float* __restrict__ dinv) {
  __shared__ int sm[256];
  int t = threadIdx.x;
  int g = blockIdx.x * 256 + t;
  if (g < N_NODES) dinv[g] = rsqrtf(deg[g]);
  int v = (g < N_NODES) ? counts[g] : 0;
  sm[t] = v;
  __syncthreads();
  for (int o = 1; o < 256; o <<= 1) {
    int add = (t >= o) ? sm[t - o] : 0;
    __syncthreads();
    sm[t] += add;
    __syncthreads();
  }
  if (g < N_NODES) incl[g] = sm[t];
  if (t == 255) part[blockIdx.x] = sm[255];
}

__global__ void k_scan2(int* __restrict__ part, int nb) {
  __shared__ int sm[128];
  int t = threadIdx.x;
  int v = (t < nb) ? part[t] : 0;
  sm[t] = v;
  __syncthreads();
  for (int o = 1; o < 128; o <<= 1) {
    int add = (t >= o) ? sm[t - o] : 0;
    __syncthreads();
    sm[t] += add;
    __syncthreads();
  }
  if (t < nb) part[t] = sm[t] - v;  // exclusive
}

__global__ void k_scan3(const int* __restrict__ incl, const int* __restrict__ counts,
                        const int* __restrict__ part, int* __restrict__ row_ptr,
                        int* __restrict__ cursor) {
  int g = blockIdx.x * 256 + threadIdx.x;
  if (g < N_NODES) {
    int start = incl[g] - counts[g] + part[blockIdx.x];
    row_ptr[g] = start;
    cursor[g] = start;
  }
  if (g == 0) row_ptr[N_NODES] = N_EDGES;
}

__global__ void k_fill(const int* __restrict__ ei, const float* __restrict__ ea,
                       const float* __restrict__ dinv, int* __restrict__ cursor,
                       int* __restrict__ csr_src, float* __restrict__ csr_w) {
  int e = blockIdx.x * 256 + threadIdx.x;
  if (e >= N_EDGES) return;
  int s = ei[e], d = ei[N_EDGES + e];
  int k = atomicAdd(&cursor[d], 1);
  csr_src[k] = s;
  csr_w[k] = dinv[s] * ea[e] * dinv[d];
}

// ---------------- fused main kernel ----------------

struct SmemT {
  union {
    struct { unsigned short a[128 * 72]; unsigned short b[128 * 72]; } ab;
    float ep[64 * 132];
  };
};

// GEMM tile: C[128x128] = A[128x256] @ BT[128 rows x 256]^T + epilogue.
// EPI 0 (init): v += bias; elu; col<128 -> hbf else c_cur.
// EPI 1 (step): gate-interleaved; fused LSTM gates via LDS transpose.
template <int EPI>
__device__ __forceinline__ void gemm_tile(
    SmemT& sm, int tid, int bm0, int bn0,
    const unsigned short* __restrict__ A, const unsigned short* __restrict__ BT,
    const float* __restrict__ bias, float* __restrict__ c_cur,
    unsigned short* __restrict__ hbf, float* __restrict__ out_t) {
  const int M = N_NODES;
  int wave = tid >> 6, lane = tid & 63;
  int wrow = (wave >> 1) * 64, wcol = (wave & 1) * 64;
  int lr = lane & 15, lq = lane >> 4;

  floatx4 acc[4][4];
#pragma unroll
  for (int i = 0; i < 4; i++)
#pragma unroll
    for (int j = 0; j < 4; j++) acc[i][j] = (floatx4){0.f, 0.f, 0.f, 0.f};

  for (int k0 = 0; k0 < 256; k0 += 64) {
    __syncthreads();
#pragma unroll
    for (int p = 0; p < 4; ++p) {
      int cch = tid + p * 256;  // 1024 chunks of 8 bf16
      int r = cch >> 3, c8 = (cch & 7) * 8;
      int grow = bm0 + r;
      float4 va = (grow < M) ? *(const float4*)(A + (size_t)grow * 256 + k0 + c8)
                             : (float4){0.f, 0.f, 0.f, 0.f};
      *(float4*)(sm.ab.a + r * 72 + c8) = va;
      float4 vb = *(const float4*)(BT + (size_t)(bn0 + r) * 256 + k0 + c8);
      *(float4*)(sm.ab.b + r * 72 + c8) = vb;
    }
    __syncthreads();
#pragma unroll
    for (int ks = 0; ks < 2; ++ks) {
      int kb = ks * 32 + lq * 8;
      bf16x8 af[4], bfr[4];
#pragma unroll
      for (int mi = 0; mi < 4; mi++)
        af[mi] = *(const bf16x8*)(sm.ab.a + (wrow + mi * 16 + lr) * 72 + kb);
#pragma unroll
      for (int ni = 0; ni < 4; ni++)
        bfr[ni] = *(const bf16x8*)(sm.ab.b + (wcol + ni * 16 + lr) * 72 + kb);
#pragma unroll
      for (int mi = 0; mi < 4; mi++)
#pragma unroll
        for (int ni = 0; ni < 4; ni++)
          acc[mi][ni] = __builtin_amdgcn_mfma_f32_16x16x32_bf16(
              af[mi], bfr[ni], acc[mi][ni], 0, 0, 0);
    }
  }
  __syncthreads();  // sm.ab dead before epilogue reuse

  if (EPI == 0) {
#pragma unroll
    for (int mi = 0; mi < 4; mi++) {
#pragma unroll
      for (int r = 0; r < 4; r++) {
        int grow = bm0 + wrow + mi * 16 + lq * 4 + r;
        if (grow >= M) continue;
#pragma unroll
        for (int ni = 0; ni < 4; ni++) {
          int gcol = bn0 + wcol + ni * 16 + lr;
          float v = acc[mi][ni][r] + bias[gcol];
          v = (v > 0.f) ? v : expm1f(v);
          if (gcol < 128) hbf[(size_t)grow * 128 + gcol] = f2bf(v);
          else c_cur[(size_t)grow * 128 + gcol - 128] = v;
        }
      }
    }
  } else {
#pragma unroll
    for (int hch = 0; hch < 2; ++hch) {
      if ((wrow >> 6) == hch) {
#pragma unroll
        for (int mi = 0; mi < 4; mi++)
#pragma unroll
          for (int r = 0; r < 4; r++) {
            int row_l = mi * 16 + lq * 4 + r;
#pragma unroll
            for (int ni = 0; ni < 4; ni++)
              sm.ep[row_l * 132 + wcol + ni * 16 + lr] = acc[mi][ni][r];
          }
      }
      __syncthreads();
#pragma unroll
      for (int it = 0; it < 8; ++it) {
        int p = tid + it * 256;
        int row_l = p >> 5, j = p & 31;
        int grow = bm0 + hch * 64 + row_l;
        if (grow < M) {
          int jg = (bn0 >> 2) + j;
          const float* eb = sm.ep + row_l * 132 + 4 * j;
          float gi = eb[0] + bias[jg];
          float gf = eb[1] + bias[128 + jg];
          float go = eb[2] + bias[256 + jg];
          float gg = eb[3] + bias[384 + jg];
          size_t o = (size_t)grow * 128 + jg;
          float cp = c_cur[o];
          float cn = sigf(gf) * cp + sigf(gi) * tanhf(gg);
          float hn = sigf(go) * tanhf(cn);
          c_cur[o] = cn;
          hbf[o] = f2bf(hn);
          out_t[o] = hn;
        }
      }
      __syncthreads();
    }
  }
}

__global__ __launch_bounds__(256, 2) void k_main(
    const float* __restrict__ h, const float* __restrict__ c,
    const float* __restrict__ bi, const float* __restrict__ bc,
    const unsigned short* __restrict__ WiT, const unsigned short* __restrict__ WcT,
    const float* __restrict__ dinv, const int* __restrict__ row_ptr,
    const int* __restrict__ csr_src, const float* __restrict__ csr_w,
    unsigned short* __restrict__ AhAc, unsigned short* __restrict__ hbf,
    float* __restrict__ c_cur, float* __restrict__ out,
    int* __restrict__ bar, int* __restrict__ gen) {
  __shared__ SmemT sm;
  int tid = threadIdx.x;
  int gwave = (blockIdx.x * 256 + tid) >> 6;  // 0..WAVES_MAIN-1
  int lane = tid & 63;
  int lgen = 0;
  unsigned int* AhAc_u = (unsigned int*)AhAc;
  const unsigned int* hbf_u = (const unsigned int*)hbf;

  // ---- Phase A: init aggregation (fp32 gather of h,c -> AhAc full rows) ----
  for (int wid = gwave; wid < N_NODES; wid += WAVES_MAIN) {
    float di = dinv[wid], dd = di * di;
    const float4* xb = (lane < 32) ? (const float4*)h : (const float4*)c;
    int lcol = lane & 31;
    float4 a = xb[(size_t)wid * 32 + lcol];
    float s0 = a.x * dd, s1 = a.y * dd, s2 = a.z * dd, s3 = a.w * dd;
    int e = row_ptr[wid], end = row_ptr[wid + 1];
#pragma unroll 2
    for (; e < end; ++e) {
      int s = csr_src[e];
      float w = csr_w[e];
      float4 v = xb[(size_t)s * 32 + lcol];
      s0 += v.x * w; s1 += v.y * w; s2 += v.z * w; s3 += v.w * w;
    }
    uint2 o;
    o.x = (unsigned int)f2bf(s0) | ((unsigned int)f2bf(s1) << 16);
    o.y = (unsigned int)f2bf(s2) | ((unsigned int)f2bf(s3) << 16);
    ((uint2*)AhAc_u)[(size_t)wid * 64 + lane] = o;
  }
  gsync(bar, gen, lgen);

  // ---- Phase B: init GEMM (157 x 2 tiles) ----
  for (int tile = blockIdx.x; tile < 157 * 2; tile += GRID_MAIN)
    gemm_tile<0>(sm, tid, (tile >> 1) * 128, (tile & 1) * 128, AhAc, WiT, bi,
                 c_cur, hbf, nullptr);
  gsync(bar, gen, lgen);

  // ---- Steps ----
  for (int t = 0; t < SEQ; ++t) {
    for (int wid = gwave; wid < N_NODES; wid += WAVES_MAIN) {
      float di = dinv[wid], dd = di * di;
      unsigned int a = hbf_u[(size_t)wid * 64 + lane];
      float s0 = bflo(a) * dd, s1 = bfhi(a) * dd;
      int e = row_ptr[wid], end = row_ptr[wid + 1];
#pragma unroll 2
      for (; e < end; ++e) {
        int s = csr_src[e];
        float w = csr_w[e];
        unsigned int v = hbf_u[(size_t)s * 64 + lane];
        s0 += bflo(v) * w;
        s1 += bfhi(v) * w;
      }
      AhAc_u[(size_t)wid * 128 + 64 + lane] =
          (unsigned int)f2bf(s0) | ((unsigned int)f2bf(s1) << 16);
    }
    gsync(bar, gen, lgen);
    float* out_t = out + (size_t)t * N_NODES * 128;
    for (int tile = blockIdx.x; tile < 157 * 4; tile += GRID_MAIN)
      gemm_tile<1>(sm, tid, (tile >> 2) * 128, (tile & 3) * 128, AhAc, WcT, bc,
                   c_cur, hbf, out_t);
    if (t != SEQ - 1) gsync(bar, gen, lgen);
  }
}

// ---------------- host launcher ----------------
extern "C" void kernel_launch(void* const* d_in, const int* in_sizes, int n_in,
                              void* d_out, int out_size, void* d_ws, size_t ws_size,
                              hipStream_t stream) {
  const float* h  = (const float*)d_in[0];
  const float* c  = (const float*)d_in[1];
  const int*   ei = (const int*)d_in[2];
  const float* ea = (const float*)d_in[3];
  const float* Wi = (const float*)d_in[4];
  const float* bi = (const float*)d_in[5];
  const float* Wc = (const float*)d_in[6];
  const float* bc = (const float*)d_in[7];
  float* out = (float*)d_out;

  char* w = (char*)d_ws;
  size_t off = 0;
  auto alloc = [&](size_t bytes) {
    void* p = w + off;
    off += (bytes + 511) & ~(size_t)511;
    return p;
  };
  float* deg           = (float*)alloc(N_NODES * 4);
  float* dinv          = (float*)alloc(N_NODES * 4);
  int* counts          = (int*)alloc(N_NODES * 4);
  int* cursor          = (int*)alloc(N_NODES * 4);
  int* scan_tmp        = (int*)alloc(N_NODES * 4);
  int* row_ptr         = (int*)alloc((N_NODES + 1) * 4);
  int* part            = (int*)alloc(1024 * 4);
  int* bar             = (int*)alloc(256 * 4);
  int* gen             = (int*)alloc(256 * 4);
  int* csr_src         = (int*)alloc(N_EDGES * 4);
  float* csr_w         = (float*)alloc(N_EDGES * 4);
  unsigned short* WiT  = (unsigned short*)alloc(256 * 256 * 2);
  unsigned short* WcT  = (unsigned short*)alloc(512 * 256 * 2);
  unsigned short* AhAc = (unsigned short*)alloc((size_t)N_NODES * 256 * 2);
  unsigned short* hbf  = (unsigned short*)alloc((size_t)N_NODES * 128 * 2);
  float* c_cur         = (float*)alloc((size_t)N_NODES * 128 * 4);

  const int NB_N = (N_NODES + 255) / 256;  // 79
  const int NB_E = (N_EDGES + 255) / 256;  // 1250

  k_prologue<<<512, 256, 0, stream>>>(Wi, Wc, WiT, WcT, deg, counts, bar, gen);
  k_deg<<<NB_E, 256, 0, stream>>>(ei, ea, deg, counts);
  k_scan1<<<NB_N, 256, 0, stream>>>(counts, scan_tmp, part, deg, dinv);
  k_scan2<<<1, 128, 0, stream>>>(part, NB_N);
  k_scan3<<<NB_N, 256, 0, stream>>>(scan_tmp, counts, part, row_ptr, cursor);
  k_fill<<<NB_E, 256, 0, stream>>>(ei, ea, dinv, cursor, csr_src, csr_w);

  k_main<<<GRID_MAIN, 256, 0, stream>>>(h, c, bi, bc, WiT, WcT, dinv, row_ptr,
                                        csr_src, csr_w, AhAc, hbf, c_cur, out,
                                        bar, gen);
}

// Round 6
// 566.969 us; speedup vs baseline: 4.9026x; 4.9026x over previous
//
#include <hip/hip_runtime.h>

#define N_NODES 20000
#define N_EDGES 320000
#define SEQ 8

typedef __attribute__((ext_vector_type(8))) short bf16x8;
typedef __attribute__((ext_vector_type(4))) float floatx4;
typedef const unsigned int __attribute__((address_space(1)))* gas_u32;
typedef unsigned int __attribute__((address_space(3)))* las_u32;

__device__ __forceinline__ unsigned short f2bf(float f) {
  unsigned int u = __builtin_bit_cast(unsigned int, f);
  return (unsigned short)((u + 0x7fffu + ((u >> 16) & 1u)) >> 16);
}
__device__ __forceinline__ float bflo(unsigned int u) {
  return __builtin_bit_cast(float, u << 16);
}
__device__ __forceinline__ float bfhi(unsigned int u) {
  return __builtin_bit_cast(float, u & 0xffff0000u);
}
__device__ __forceinline__ float sigf(float x) { return 1.f / (1.f + __expf(-x)); }

// async global->LDS, 16B per lane; LDS dest = wave-uniform base + lane*16
__device__ __forceinline__ void gl_lds16(const void* g, void* l) {
  auto gp = (gas_u32)g;
  auto lp = (las_u32)(unsigned int)(unsigned long long)l;  // strip aperture
  __builtin_amdgcn_global_load_lds(gp, lp, 16, 0, 0);
}

// ---------------- setup kernels ----------------

// deg/counts init + weight transpose/convert. WiT[n][k]=Wi[k][n] (256x256).
// W1T/W2T gate-interleaved: n'=4j+gate, orig=gate*128+j; W1 = Wc rows 0..127
// (h-static part), W2 = Wc rows 128..255 (h_cur part). bcp = b_cell permuted.
__global__ void k_prologue(const float* __restrict__ Wi,
                           const float* __restrict__ Wc,
                           const float* __restrict__ bc,
                           unsigned short* __restrict__ WiT,
                           unsigned short* __restrict__ W1T,
                           unsigned short* __restrict__ W2T,
                           float* __restrict__ bcp,
                           float* __restrict__ deg, int* __restrict__ counts) {
  int idx = blockIdx.x * 256 + threadIdx.x;  // 0..131071
  if (idx < N_NODES) { deg[idx] = 1.0f; counts[idx] = 0; }
  if (idx < 65536) {
    int n = idx >> 8, k = idx & 255;
    WiT[n * 256 + k] = f2bf(Wi[k * 256 + n]);
  }
  if (idx < 512) bcp[idx] = bc[((idx & 3) << 7) | (idx >> 2)];
  int n2 = idx >> 8, k2 = idx & 255;  // n2 0..511
  if (k2 < 128) {
    int orig = ((n2 & 3) << 7) | (n2 >> 2);
    W1T[n2 * 128 + k2] = f2bf(Wc[k2 * 512 + orig]);
    W2T[n2 * 128 + k2] = f2bf(Wc[(k2 + 128) * 512 + orig]);
  }
}

__global__ void k_deg(const int* __restrict__ ei, const float* __restrict__ ea,
                      float* __restrict__ deg, int* __restrict__ counts) {
  int e = blockIdx.x * 256 + threadIdx.x;
  if (e >= N_EDGES) return;
  int d = ei[N_EDGES + e];
  atomicAdd(&deg[d], ea[e]);
  atomicAdd(&counts[d], 1);
}

__global__ void k_scan1(const int* __restrict__ counts, int* __restrict__ incl,
                        int* __restrict__ part, const float* __restrict__ deg,
                        float* __restrict__ dinv) {
  __shared__ int sm[256];
  int t = threadIdx.x;
  int g = blockIdx.x * 256 + t;
  if (g < N_NODES) dinv[g] = rsqrtf(deg[g]);
  int v = (g < N_NODES) ? counts[g] : 0;
  sm[t] = v;
  __syncthreads();
  for (int o = 1; o < 256; o <<= 1) {
    int add = (t >= o) ? sm[t - o] : 0;
    __syncthreads();
    sm[t] += add;
    __syncthreads();
  }
  if (g < N_NODES) incl[g] = sm[t];
  if (t == 255) part[blockIdx.x] = sm[255];
}

__global__ void k_scan2(int* __restrict__ part, int nb) {
  __shared__ int sm[128];
  int t = threadIdx.x;
  int v = (t < nb) ? part[t] : 0;
  sm[t] = v;
  __syncthreads();
  for (int o = 1; o < 128; o <<= 1) {
    int add = (t >= o) ? sm[t - o] : 0;
    __syncthreads();
    sm[t] += add;
    __syncthreads();
  }
  if (t < nb) part[t] = sm[t] - v;  // exclusive
}

__global__ void k_scan3(const int* __restrict__ incl, const int* __restrict__ counts,
                        const int* __restrict__ part, int* __restrict__ row_ptr,
                        int* __restrict__ cursor) {
  int g = blockIdx.x * 256 + threadIdx.x;
  if (g < N_NODES) {
    int start = incl[g] - counts[g] + part[blockIdx.x];
    row_ptr[g] = start;
    cursor[g] = start;
  }
  if (g == 0) row_ptr[N_NODES] = N_EDGES;
}

__global__ void k_fill(const int* __restrict__ ei, const float* __restrict__ ea,
                       const float* __restrict__ dinv, int* __restrict__ cursor,
                       int* __restrict__ csr_src, float* __restrict__ csr_w) {
  int e = blockIdx.x * 256 + threadIdx.x;
  if (e >= N_EDGES) return;
  int s = ei[e], d = ei[N_EDGES + e];
  int k = atomicAdd(&cursor[d], 1);
  csr_src[k] = s;
  csr_w[k] = dinv[s] * ea[e] * dinv[d];
}

// ---------------- aggregation (gather via CSR, one wave per node) -------------

// init: gather fp32 h,c -> AhAc rows (256 bf16: cols 0..127 Ah, 128..255 Ac)
__global__ __launch_bounds__(256) void k_agg_init(
    const float* __restrict__ h, const float* __restrict__ c,
    unsigned int* __restrict__ AhAc_u, const float* __restrict__ dinv,
    const int* __restrict__ row_ptr, const int* __restrict__ csr_src,
    const float* __restrict__ csr_w) {
  int wid = (blockIdx.x * 256 + threadIdx.x) >> 6;
  int lane = threadIdx.x & 63;
  if (wid >= N_NODES) return;
  float di = dinv[wid], dd = di * di;
  const float4* xb = (lane < 32) ? (const float4*)h : (const float4*)c;
  int lcol = lane & 31;
  float4 a = xb[(size_t)wid * 32 + lcol];
  float s0 = a.x * dd, s1 = a.y * dd, s2 = a.z * dd, s3 = a.w * dd;
  int e = row_ptr[wid], end = row_ptr[wid + 1];
#pragma unroll 2
  for (; e < end; ++e) {
    int s = csr_src[e];
    float w = csr_w[e];
    float4 v = xb[(size_t)s * 32 + lcol];
    s0 += v.x * w; s1 += v.y * w; s2 += v.z * w; s3 += v.w * w;
  }
  uint2 o;
  o.x = (unsigned int)f2bf(s0) | ((unsigned int)f2bf(s1) << 16);
  o.y = (unsigned int)f2bf(s2) | ((unsigned int)f2bf(s3) << 16);
  ((uint2*)AhAc_u)[(size_t)wid * 64 + lane] = o;
}

// step: gather hbf rows (128 bf16) -> compact Aht rows
__global__ __launch_bounds__(256) void k_agg_step(
    const unsigned int* __restrict__ hbf_u, unsigned int* __restrict__ Aht_u,
    const float* __restrict__ dinv, const int* __restrict__ row_ptr,
    const int* __restrict__ csr_src, const float* __restrict__ csr_w) {
  int wid = (blockIdx.x * 256 + threadIdx.x) >> 6;
  int lane = threadIdx.x & 63;
  if (wid >= N_NODES) return;
  float di = dinv[wid], dd = di * di;
  unsigned int a = hbf_u[(size_t)wid * 64 + lane];
  float s0 = bflo(a) * dd, s1 = bfhi(a) * dd;
  int e = row_ptr[wid], end = row_ptr[wid + 1];
#pragma unroll 2
  for (; e < end; ++e) {
    int s = csr_src[e];
    float w = csr_w[e];
    unsigned int v = hbf_u[(size_t)s * 64 + lane];
    s0 += bflo(v) * w;
    s1 += bfhi(v) * w;
  }
  Aht_u[(size_t)wid * 64 + lane] =
      (unsigned int)f2bf(s0) | ((unsigned int)f2bf(s1) << 16);
}

// ---------------- bf16 MFMA GEMM with global_load_lds + XOR-swizzled LDS -----
// C[128x128] = A[128xKK](row-stride LDA) @ BT[128 of KK]^T + epilogue.
// LDS layout: row-stride 64 shorts (128B, no pad); chunk slot s of row r holds
// global chunk (s ^ (r&7)) -- swizzle absorbed in per-lane global address.
// EPI 0 (init, KK=256): v += bias[gcol]; elu; col<128 -> hbf else c_cur.
// EPI 1 (Kbuf build, KK=128): Kbuf = v + bcp[gcol]  (gate-interleaved cols).
// EPI 2 (step, KK=128): gates fused; gi..gg = acc + Kbuf (has bias).
template <int EPI, int KK, int LDA>
__global__ __launch_bounds__(256) void k_gemm(
    const unsigned short* __restrict__ A, const unsigned short* __restrict__ BT,
    const float* __restrict__ bias, const float* __restrict__ Kbuf,
    float* __restrict__ c_cur, unsigned short* __restrict__ hbf,
    float* __restrict__ out0) {
  __shared__ __align__(16) union {
    struct { unsigned short a[128 * 64]; unsigned short b[128 * 64]; } ab;
    float ep[64 * 132];
  } sm;
  const int M = N_NODES;
  int tid = threadIdx.x;
  int bm0 = blockIdx.x * 128, bn0 = blockIdx.y * 128;
  int wave = tid >> 6, lane = tid & 63;
  int wrow = (wave >> 1) * 64, wcol = (wave & 1) * 64;
  int lr = lane & 15, lq = lane >> 4;
  int key = lr & 7;

  // staging lane roles: 8 lanes/row, 8 rows/wave/call
  int lr8 = lane >> 3, cq = lane & 7;
  int gq8 = (cq ^ lr8) * 8;  // swizzled global chunk offset (shorts)

  floatx4 acc[4][4];
#pragma unroll
  for (int i = 0; i < 4; i++)
#pragma unroll
    for (int j = 0; j < 4; j++) acc[i][j] = (floatx4){0.f, 0.f, 0.f, 0.f};

  for (int k0 = 0; k0 < KK; k0 += 64) {
    __syncthreads();
#pragma unroll
    for (int p = 0; p < 4; ++p) {
      int row = p * 32 + wave * 8;        // wave-uniform base row
      int ra = bm0 + row + lr8;
      if (ra > M - 1) ra = M - 1;         // clamp: junk rows never stored
      gl_lds16(A + (size_t)ra * LDA + k0 + gq8, sm.ab.a + row * 64);
      gl_lds16(BT + (size_t)(bn0 + row + lr8) * KK + k0 + gq8,
               sm.ab.b + row * 64);
    }
    __syncthreads();
#pragma unroll
    for (int ks = 0; ks < 2; ++ks) {
      int q = ks * 4 + lq;
      int slot = (q ^ key) << 3;
      bf16x8 af[4], bfr[4];
#pragma unroll
      for (int mi = 0; mi < 4; mi++)
        af[mi] = *(const bf16x8*)(sm.ab.a + (wrow + mi * 16 + lr) * 64 + slot);
#pragma unroll
      for (int ni = 0; ni < 4; ni++)
        bfr[ni] = *(const bf16x8*)(sm.ab.b + (wcol + ni * 16 + lr) * 64 + slot);
#pragma unroll
      for (int mi = 0; mi < 4; mi++)
#pragma unroll
        for (int ni = 0; ni < 4; ni++)
          acc[mi][ni] = __builtin_amdgcn_mfma_f32_16x16x32_bf16(
              af[mi], bfr[ni], acc[mi][ni], 0, 0, 0);
    }
  }
  __syncthreads();  // sm.ab dead before epilogue reuse

  if (EPI == 0) {
#pragma unroll
    for (int mi = 0; mi < 4; mi++) {
#pragma unroll
      for (int r = 0; r < 4; r++) {
        int grow = bm0 + wrow + mi * 16 + lq * 4 + r;
        if (grow >= M) continue;
#pragma unroll
        for (int ni = 0; ni < 4; ni++) {
          int gcol = bn0 + wcol + ni * 16 + lr;
          float v = acc[mi][ni][r] + bias[gcol];
          v = (v > 0.f) ? v : expm1f(v);
          if (gcol < 128) hbf[(size_t)grow * 128 + gcol] = f2bf(v);
          else c_cur[(size_t)grow * 128 + gcol - 128] = v;
        }
      }
    }
  } else if (EPI == 1) {
#pragma unroll
    for (int mi = 0; mi < 4; mi++) {
#pragma unroll
      for (int r = 0; r < 4; r++) {
        int grow = bm0 + wrow + mi * 16 + lq * 4 + r;
        if (grow >= M) continue;
#pragma unroll
        for (int ni = 0; ni < 4; ni++) {
          int gcol = bn0 + wcol + ni * 16 + lr;
          out0[(size_t)grow * 512 + gcol] = acc[mi][ni][r] + bias[gcol];
        }
      }
    }
  } else {
    // two 64-row chunks through LDS transpose; fused LSTM gates
#pragma unroll
    for (int hch = 0; hch < 2; ++hch) {
      if ((wrow >> 6) == hch) {
#pragma unroll
        for (int mi = 0; mi < 4; mi++)
#pragma unroll
          for (int r = 0; r < 4; r++) {
            int row_l = mi * 16 + lq * 4 + r;
#pragma unroll
            for (int ni = 0; ni < 4; ni++)
              sm.ep[row_l * 132 + wcol + ni * 16 + lr] = acc[mi][ni][r];
          }
      }
      __syncthreads();
#pragma unroll
      for (int it = 0; it < 8; ++it) {
        int p = tid + it * 256;
        int row_l = p >> 5, j = p & 31;
        int grow = bm0 + hch * 64 + row_l;
        if (grow < M) {
          int jg = (bn0 >> 2) + j;
          const float* eb = sm.ep + row_l * 132 + 4 * j;
          float4 kb = *(const float4*)&Kbuf[(size_t)grow * 512 + bn0 + 4 * j];
          float gi = eb[0] + kb.x;
          float gf = eb[1] + kb.y;
          float go = eb[2] + kb.z;
          float gg = eb[3] + kb.w;
          size_t o = (size_t)grow * 128 + jg;
          float cp = c_cur[o];
          float cn = sigf(gf) * cp + sigf(gi) * tanhf(gg);
          float hn = sigf(go) * tanhf(cn);
          c_cur[o] = cn;
          hbf[o] = f2bf(hn);
          out0[o] = hn;
        }
      }
      __syncthreads();
    }
  }
}

// ---------------- host launcher ----------------
extern "C" void kernel_launch(void* const* d_in, const int* in_sizes, int n_in,
                              void* d_out, int out_size, void* d_ws, size_t ws_size,
                              hipStream_t stream) {
  const float* h  = (const float*)d_in[0];
  const float* c  = (const float*)d_in[1];
  const int*   ei = (const int*)d_in[2];
  const float* ea = (const float*)d_in[3];
  const float* Wi = (const float*)d_in[4];
  const float* bi = (const float*)d_in[5];
  const float* Wc = (const float*)d_in[6];
  const float* bc = (const float*)d_in[7];
  float* out = (float*)d_out;

  char* w = (char*)d_ws;
  size_t off = 0;
  auto alloc = [&](size_t bytes) {
    void* p = w + off;
    off += (bytes + 511) & ~(size_t)511;
    return p;
  };
  float* deg           = (float*)alloc(N_NODES * 4);
  float* dinv          = (float*)alloc(N_NODES * 4);
  int* counts          = (int*)alloc(N_NODES * 4);
  int* cursor          = (int*)alloc(N_NODES * 4);
  int* scan_tmp        = (int*)alloc(N_NODES * 4);
  int* row_ptr         = (int*)alloc((N_NODES + 1) * 4);
  int* part            = (int*)alloc(1024 * 4);
  int* csr_src         = (int*)alloc(N_EDGES * 4);
  float* csr_w         = (float*)alloc(N_EDGES * 4);
  unsigned short* WiT  = (unsigned short*)alloc(256 * 256 * 2);
  unsigned short* W1T  = (unsigned short*)alloc(512 * 128 * 2);
  unsigned short* W2T  = (unsigned short*)alloc(512 * 128 * 2);
  float* bcp           = (float*)alloc(512 * 4);
  unsigned short* AhAc = (unsigned short*)alloc((size_t)N_NODES * 256 * 2);
  unsigned short* Aht  = (unsigned short*)alloc((size_t)N_NODES * 128 * 2);
  unsigned short* hbf  = (unsigned short*)alloc((size_t)N_NODES * 128 * 2);
  float* c_cur         = (float*)alloc((size_t)N_NODES * 128 * 4);
  float* Kbuf          = (float*)alloc((size_t)N_NODES * 512 * 4);

  const int NB_N = (N_NODES + 255) / 256;  // 79
  const int NB_E = (N_EDGES + 255) / 256;  // 1250
  const int NB_AGG = N_NODES * 64 / 256;   // 5000
  const int MB = (N_NODES + 127) / 128;    // 157

  k_prologue<<<512, 256, 0, stream>>>(Wi, Wc, bc, WiT, W1T, W2T, bcp, deg,
                                      counts);
  k_deg<<<NB_E, 256, 0, stream>>>(ei, ea, deg, counts);
  k_scan1<<<NB_N, 256, 0, stream>>>(counts, scan_tmp, part, deg, dinv);
  k_scan2<<<1, 128, 0, stream>>>(part, NB_N);
  k_scan3<<<NB_N, 256, 0, stream>>>(scan_tmp, counts, part, row_ptr, cursor);
  k_fill<<<NB_E, 256, 0, stream>>>(ei, ea, dinv, cursor, csr_src, csr_w);

  k_agg_init<<<NB_AGG, 256, 0, stream>>>(h, c, (unsigned int*)AhAc, dinv,
                                         row_ptr, csr_src, csr_w);
  // states = elu([Ah|Ac]@Wi + bi) -> hbf, c_cur
  k_gemm<0, 256, 256><<<dim3(MB, 2), 256, 0, stream>>>(
      AhAc, WiT, bi, nullptr, c_cur, hbf, nullptr);
  // Kbuf = Ah@W1 + bcp (gate-interleaved), A = AhAc cols 0..127
  k_gemm<1, 128, 256><<<dim3(MB, 4), 256, 0, stream>>>(
      AhAc, W1T, bcp, nullptr, nullptr, nullptr, Kbuf);

  for (int t = 0; t < SEQ; ++t) {
    k_agg_step<<<NB_AGG, 256, 0, stream>>>((unsigned int*)hbf,
                                           (unsigned int*)Aht, dinv, row_ptr,
                                           csr_src, csr_w);
    k_gemm<2, 128, 128><<<dim3(MB, 4), 256, 0, stream>>>(
        Aht, W2T, nullptr, Kbuf, c_cur, hbf, out + (size_t)t * N_NODES * 128);
  }
}

// Round 7
// 534.654 us; speedup vs baseline: 5.1989x; 1.0604x over previous
//
#include <hip/hip_runtime.h>

#define N_NODES 20000
#define N_EDGES 320000
#define SEQ 8

typedef __attribute__((ext_vector_type(8))) short bf16x8;
typedef __attribute__((ext_vector_type(4))) float floatx4;
typedef const unsigned int __attribute__((address_space(1)))* gas_u32;
typedef unsigned int __attribute__((address_space(3)))* las_u32;

__device__ __forceinline__ unsigned short f2bf(float f) {
  unsigned int u = __builtin_bit_cast(unsigned int, f);
  return (unsigned short)((u + 0x7fffu + ((u >> 16) & 1u)) >> 16);
}
__device__ __forceinline__ float bflo(unsigned int u) {
  return __builtin_bit_cast(float, u << 16);
}
__device__ __forceinline__ float bfhi(unsigned int u) {
  return __builtin_bit_cast(float, u & 0xffff0000u);
}
__device__ __forceinline__ float sigf(float x) { return 1.f / (1.f + __expf(-x)); }

// async global->LDS, 16B per lane; LDS dest = wave-uniform base + lane*16
__device__ __forceinline__ void gl_lds16(const void* g, void* l) {
  auto gp = (gas_u32)g;
  auto lp = (las_u32)(unsigned int)(unsigned long long)l;  // strip aperture
  __builtin_amdgcn_global_load_lds(gp, lp, 16, 0, 0);
}

// ---------------- setup kernels ----------------

// deg/counts init + weight transpose/convert. WiT[n][k]=Wi[k][n] (256x256).
// W1T/W2T gate-interleaved: n'=4j+gate, orig=gate*128+j; W1 = Wc rows 0..127,
// W2 = Wc rows 128..255. bcp = b_cell permuted.
__global__ void k_prologue(const float* __restrict__ Wi,
                           const float* __restrict__ Wc,
                           const float* __restrict__ bc,
                           unsigned short* __restrict__ WiT,
                           unsigned short* __restrict__ W1T,
                           unsigned short* __restrict__ W2T,
                           float* __restrict__ bcp,
                           float* __restrict__ deg, int* __restrict__ counts) {
  int idx = blockIdx.x * 256 + threadIdx.x;  // 0..131071
  if (idx < N_NODES) { deg[idx] = 1.0f; counts[idx] = 0; }
  if (idx < 65536) {
    int n = idx >> 8, k = idx & 255;
    WiT[n * 256 + k] = f2bf(Wi[k * 256 + n]);
  }
  if (idx < 512) bcp[idx] = bc[((idx & 3) << 7) | (idx >> 2)];
  int n2 = idx >> 8, k2 = idx & 255;  // n2 0..511
  if (k2 < 128) {
    int orig = ((n2 & 3) << 7) | (n2 >> 2);
    W1T[n2 * 128 + k2] = f2bf(Wc[k2 * 512 + orig]);
    W2T[n2 * 128 + k2] = f2bf(Wc[(k2 + 128) * 512 + orig]);
  }
}

__global__ void k_deg(const int* __restrict__ ei, const float* __restrict__ ea,
                      float* __restrict__ deg, int* __restrict__ counts) {
  int e = blockIdx.x * 256 + threadIdx.x;
  if (e >= N_EDGES) return;
  int d = ei[N_EDGES + e];
  atomicAdd(&deg[d], ea[e]);
  atomicAdd(&counts[d], 1);
}

// single-block scan: counts -> exclusive row_ptr/cursor; dinv = rsqrt(deg)
__global__ __launch_bounds__(1024) void k_scan(
    const int* __restrict__ counts, const float* __restrict__ deg,
    float* __restrict__ dinv, int* __restrict__ row_ptr,
    int* __restrict__ cursor) {
  __shared__ int sm[1024];
  int t = threadIdx.x;
  int base = t * 20;
  int local[20];
  int s = 0;
#pragma unroll
  for (int i = 0; i < 20; ++i) {
    int g = base + i;
    int v = (g < N_NODES) ? counts[g] : 0;
    local[i] = v;
    s += v;
  }
  sm[t] = s;
  __syncthreads();
  for (int o = 1; o < 1024; o <<= 1) {
    int add = (t >= o) ? sm[t - o] : 0;
    __syncthreads();
    sm[t] += add;
    __syncthreads();
  }
  int run = sm[t] - s;  // exclusive prefix of this thread's chunk
#pragma unroll
  for (int i = 0; i < 20; ++i) {
    int g = base + i;
    if (g < N_NODES) {
      row_ptr[g] = run;
      cursor[g] = run;
      dinv[g] = rsqrtf(deg[g]);
    }
    run += local[i];
  }
  if (t == 0) row_ptr[N_NODES] = N_EDGES;
}

__global__ void k_fill(const int* __restrict__ ei, const float* __restrict__ ea,
                       const float* __restrict__ dinv, int* __restrict__ cursor,
                       int* __restrict__ csr_src, float* __restrict__ csr_w) {
  int e = blockIdx.x * 256 + threadIdx.x;
  if (e >= N_EDGES) return;
  int s = ei[e], d = ei[N_EDGES + e];
  int k = atomicAdd(&cursor[d], 1);
  csr_src[k] = s;
  csr_w[k] = dinv[s] * ea[e] * dinv[d];
}

// ---------------- aggregation (gather via CSR, one wave per node) -------------
// Edge lists are broadcast via __shfl so row gathers issue independently (MLP).

// init: gather fp32 h,c -> AhAc rows (256 bf16: cols 0..127 Ah, 128..255 Ac)
__global__ __launch_bounds__(256) void k_agg_init(
    const float* __restrict__ h, const float* __restrict__ c,
    unsigned int* __restrict__ AhAc_u, const float* __restrict__ dinv,
    const int* __restrict__ row_ptr, const int* __restrict__ csr_src,
    const float* __restrict__ csr_w) {
  int wid = (blockIdx.x * 256 + threadIdx.x) >> 6;
  int lane = threadIdx.x & 63;
  if (wid >= N_NODES) return;
  float di = dinv[wid], dd = di * di;
  const float4* xb = (lane < 32) ? (const float4*)h : (const float4*)c;
  int lcol = lane & 31;
  float4 a = xb[(size_t)wid * 32 + lcol];
  float s0 = a.x * dd, s1 = a.y * dd, s2 = a.z * dd, s3 = a.w * dd;
  int e0 = row_ptr[wid], end = row_ptr[wid + 1];
  for (int base = e0; base < end; base += 64) {
    int n = end - base;
    if (n > 64) n = 64;
    int sl = 0;
    float wl = 0.f;
    if (base + lane < end) {
      sl = csr_src[base + lane];
      wl = csr_w[base + lane];
    }
    int j = 0;
    for (; j + 4 <= n; j += 4) {
      int sa = __shfl(sl, j), sb = __shfl(sl, j + 1);
      int sc = __shfl(sl, j + 2), sd = __shfl(sl, j + 3);
      float wa = __shfl(wl, j), wb = __shfl(wl, j + 1);
      float wc = __shfl(wl, j + 2), wd = __shfl(wl, j + 3);
      float4 va = xb[(size_t)sa * 32 + lcol];
      float4 vb = xb[(size_t)sb * 32 + lcol];
      float4 vc = xb[(size_t)sc * 32 + lcol];
      float4 vd = xb[(size_t)sd * 32 + lcol];
      s0 += va.x * wa; s1 += va.y * wa; s2 += va.z * wa; s3 += va.w * wa;
      s0 += vb.x * wb; s1 += vb.y * wb; s2 += vb.z * wb; s3 += vb.w * wb;
      s0 += vc.x * wc; s1 += vc.y * wc; s2 += vc.z * wc; s3 += vc.w * wc;
      s0 += vd.x * wd; s1 += vd.y * wd; s2 += vd.z * wd; s3 += vd.w * wd;
    }
    for (; j < n; ++j) {
      int sa = __shfl(sl, j);
      float wa = __shfl(wl, j);
      float4 va = xb[(size_t)sa * 32 + lcol];
      s0 += va.x * wa; s1 += va.y * wa; s2 += va.z * wa; s3 += va.w * wa;
    }
  }
  uint2 o;
  o.x = (unsigned int)f2bf(s0) | ((unsigned int)f2bf(s1) << 16);
  o.y = (unsigned int)f2bf(s2) | ((unsigned int)f2bf(s3) << 16);
  ((uint2*)AhAc_u)[(size_t)wid * 64 + lane] = o;
}

// step: gather hbf rows (128 bf16) -> compact Aht rows
__global__ __launch_bounds__(256) void k_agg_step(
    const unsigned int* __restrict__ hbf_u, unsigned int* __restrict__ Aht_u,
    const float* __restrict__ dinv, const int* __restrict__ row_ptr,
    const int* __restrict__ csr_src, const float* __restrict__ csr_w) {
  int wid = (blockIdx.x * 256 + threadIdx.x) >> 6;
  int lane = threadIdx.x & 63;
  if (wid >= N_NODES) return;
  float di = dinv[wid], dd = di * di;
  unsigned int a = hbf_u[(size_t)wid * 64 + lane];
  float s0 = bflo(a) * dd, s1 = bfhi(a) * dd;
  int e0 = row_ptr[wid], end = row_ptr[wid + 1];
  for (int base = e0; base < end; base += 64) {
    int n = end - base;
    if (n > 64) n = 64;
    int sl = 0;
    float wl = 0.f;
    if (base + lane < end) {
      sl = csr_src[base + lane];
      wl = csr_w[base + lane];
    }
    int j = 0;
    for (; j + 4 <= n; j += 4) {
      int sa = __shfl(sl, j), sb = __shfl(sl, j + 1);
      int sc = __shfl(sl, j + 2), sd = __shfl(sl, j + 3);
      float wa = __shfl(wl, j), wb = __shfl(wl, j + 1);
      float wc = __shfl(wl, j + 2), wd = __shfl(wl, j + 3);
      unsigned int va = hbf_u[(size_t)sa * 64 + lane];
      unsigned int vb = hbf_u[(size_t)sb * 64 + lane];
      unsigned int vc = hbf_u[(size_t)sc * 64 + lane];
      unsigned int vd = hbf_u[(size_t)sd * 64 + lane];
      s0 += bflo(va) * wa; s1 += bfhi(va) * wa;
      s0 += bflo(vb) * wb; s1 += bfhi(vb) * wb;
      s0 += bflo(vc) * wc; s1 += bfhi(vc) * wc;
      s0 += bflo(vd) * wd; s1 += bfhi(vd) * wd;
    }
    for (; j < n; ++j) {
      int sa = __shfl(sl, j);
      float wa = __shfl(wl, j);
      unsigned int va = hbf_u[(size_t)sa * 64 + lane];
      s0 += bflo(va) * wa; s1 += bfhi(va) * wa;
    }
  }
  Aht_u[(size_t)wid * 64 + lane] =
      (unsigned int)f2bf(s0) | ((unsigned int)f2bf(s1) << 16);
}

// ---------------- bf16 MFMA GEMM with global_load_lds + XOR-swizzled LDS -----
// C[128x128] = A[128xKK](row-stride LDA) @ BT[128 of KK]^T + epilogue.
// EPI 0 (init, KK=256): v += bias[gcol]; elu; col<128 -> hbf else c_cur.
// EPI 1 (Kbuf build, KK=128): Kbuf = v + bcp[gcol]  (gate-interleaved cols).
// EPI 2 (step, KK=128): gates fused; gi..gg = acc + Kbuf (has bias).
template <int EPI, int KK, int LDA>
__global__ __launch_bounds__(256) void k_gemm(
    const unsigned short* __restrict__ A, const unsigned short* __restrict__ BT,
    const float* __restrict__ bias, const float* __restrict__ Kbuf,
    float* __restrict__ c_cur, unsigned short* __restrict__ hbf,
    float* __restrict__ out0) {
  __shared__ __align__(16) union {
    struct { unsigned short a[128 * 64]; unsigned short b[128 * 64]; } ab;
    float ep[64 * 132];
  } sm;
  const int M = N_NODES;
  int tid = threadIdx.x;
  int bm0 = blockIdx.x * 128, bn0 = blockIdx.y * 128;
  int wave = tid >> 6, lane = tid & 63;
  int wrow = (wave >> 1) * 64, wcol = (wave & 1) * 64;
  int lr = lane & 15, lq = lane >> 4;
  int key = lr & 7;

  // staging lane roles: 8 lanes/row, 8 rows/wave/call
  int lr8 = lane >> 3, cq = lane & 7;
  int gq8 = (cq ^ lr8) * 8;  // swizzled global chunk offset (shorts)

  floatx4 acc[4][4];
#pragma unroll
  for (int i = 0; i < 4; i++)
#pragma unroll
    for (int j = 0; j < 4; j++) acc[i][j] = (floatx4){0.f, 0.f, 0.f, 0.f};

  for (int k0 = 0; k0 < KK; k0 += 64) {
    __syncthreads();
#pragma unroll
    for (int p = 0; p < 4; ++p) {
      int row = p * 32 + wave * 8;        // wave-uniform base row
      int ra = bm0 + row + lr8;
      if (ra > M - 1) ra = M - 1;         // clamp: junk rows never stored
      gl_lds16(A + (size_t)ra * LDA + k0 + gq8, sm.ab.a + row * 64);
      gl_lds16(BT + (size_t)(bn0 + row + lr8) * KK + k0 + gq8,
               sm.ab.b + row * 64);
    }
    __syncthreads();
#pragma unroll
    for (int ks = 0; ks < 2; ++ks) {
      int q = ks * 4 + lq;
      int slot = (q ^ key) << 3;
      bf16x8 af[4], bfr[4];
#pragma unroll
      for (int mi = 0; mi < 4; mi++)
        af[mi] = *(const bf16x8*)(sm.ab.a + (wrow + mi * 16 + lr) * 64 + slot);
#pragma unroll
      for (int ni = 0; ni < 4; ni++)
        bfr[ni] = *(const bf16x8*)(sm.ab.b + (wcol + ni * 16 + lr) * 64 + slot);
#pragma unroll
      for (int mi = 0; mi < 4; mi++)
#pragma unroll
        for (int ni = 0; ni < 4; ni++)
          acc[mi][ni] = __builtin_amdgcn_mfma_f32_16x16x32_bf16(
              af[mi], bfr[ni], acc[mi][ni], 0, 0, 0);
    }
  }
  __syncthreads();  // sm.ab dead before epilogue reuse

  if (EPI == 0) {
#pragma unroll
    for (int mi = 0; mi < 4; mi++) {
#pragma unroll
      for (int r = 0; r < 4; r++) {
        int grow = bm0 + wrow + mi * 16 + lq * 4 + r;
        if (grow >= M) continue;
#pragma unroll
        for (int ni = 0; ni < 4; ni++) {
          int gcol = bn0 + wcol + ni * 16 + lr;
          float v = acc[mi][ni][r] + bias[gcol];
          v = (v > 0.f) ? v : expm1f(v);
          if (gcol < 128) hbf[(size_t)grow * 128 + gcol] = f2bf(v);
          else c_cur[(size_t)grow * 128 + gcol - 128] = v;
        }
      }
    }
  } else if (EPI == 1) {
#pragma unroll
    for (int mi = 0; mi < 4; mi++) {
#pragma unroll
      for (int r = 0; r < 4; r++) {
        int grow = bm0 + wrow + mi * 16 + lq * 4 + r;
        if (grow >= M) continue;
#pragma unroll
        for (int ni = 0; ni < 4; ni++) {
          int gcol = bn0 + wcol + ni * 16 + lr;
          out0[(size_t)grow * 512 + gcol] = acc[mi][ni][r] + bias[gcol];
        }
      }
    }
  } else {
    // two 64-row chunks through LDS transpose; fused LSTM gates
#pragma unroll
    for (int hch = 0; hch < 2; ++hch) {
      if ((wrow >> 6) == hch) {
#pragma unroll
        for (int mi = 0; mi < 4; mi++)
#pragma unroll
          for (int r = 0; r < 4; r++) {
            int row_l = mi * 16 + lq * 4 + r;
#pragma unroll
            for (int ni = 0; ni < 4; ni++)
              sm.ep[row_l * 132 + wcol + ni * 16 + lr] = acc[mi][ni][r];
          }
      }
      __syncthreads();
#pragma unroll
      for (int it = 0; it < 8; ++it) {
        int p = tid + it * 256;
        int row_l = p >> 5, j = p & 31;
        int grow = bm0 + hch * 64 + row_l;
        if (grow < M) {
          int jg = (bn0 >> 2) + j;
          const float* eb = sm.ep + row_l * 132 + 4 * j;
          float4 kb = *(const float4*)&Kbuf[(size_t)grow * 512 + bn0 + 4 * j];
          float gi = eb[0] + kb.x;
          float gf = eb[1] + kb.y;
          float go = eb[2] + kb.z;
          float gg = eb[3] + kb.w;
          size_t o = (size_t)grow * 128 + jg;
          float cp = c_cur[o];
          float cn = sigf(gf) * cp + sigf(gi) * tanhf(gg);
          float hn = sigf(go) * tanhf(cn);
          c_cur[o] = cn;
          hbf[o] = f2bf(hn);
          out0[o] = hn;
        }
      }
      __syncthreads();
    }
  }
}

// ---------------- host launcher ----------------
extern "C" void kernel_launch(void* const* d_in, const int* in_sizes, int n_in,
                              void* d_out, int out_size, void* d_ws, size_t ws_size,
                              hipStream_t stream) {
  const float* h  = (const float*)d_in[0];
  const float* c  = (const float*)d_in[1];
  const int*   ei = (const int*)d_in[2];
  const float* ea = (const float*)d_in[3];
  const float* Wi = (const float*)d_in[4];
  const float* bi = (const float*)d_in[5];
  const float* Wc = (const float*)d_in[6];
  const float* bc = (const float*)d_in[7];
  float* out = (float*)d_out;

  char* w = (char*)d_ws;
  size_t off = 0;
  auto alloc = [&](size_t bytes) {
    void* p = w + off;
    off += (bytes + 511) & ~(size_t)511;
    return p;
  };
  float* deg           = (float*)alloc(N_NODES * 4);
  float* dinv          = (float*)alloc(N_NODES * 4);
  int* counts          = (int*)alloc(N_NODES * 4);
  int* cursor          = (int*)alloc(N_NODES * 4);
  int* row_ptr         = (int*)alloc((N_NODES + 1) * 4);
  int* csr_src         = (int*)alloc(N_EDGES * 4);
  float* csr_w         = (float*)alloc(N_EDGES * 4);
  unsigned short* WiT  = (unsigned short*)alloc(256 * 256 * 2);
  unsigned short* W1T  = (unsigned short*)alloc(512 * 128 * 2);
  unsigned short* W2T  = (unsigned short*)alloc(512 * 128 * 2);
  float* bcp           = (float*)alloc(512 * 4);
  unsigned short* AhAc = (unsigned short*)alloc((size_t)N_NODES * 256 * 2);
  unsigned short* Aht  = (unsigned short*)alloc((size_t)N_NODES * 128 * 2);
  unsigned short* hbf  = (unsigned short*)alloc((size_t)N_NODES * 128 * 2);
  float* c_cur         = (float*)alloc((size_t)N_NODES * 128 * 4);
  float* Kbuf          = (float*)alloc((size_t)N_NODES * 512 * 4);

  const int NB_E = (N_EDGES + 255) / 256;  // 1250
  const int NB_AGG = N_NODES * 64 / 256;   // 5000
  const int MB = (N_NODES + 127) / 128;    // 157

  k_prologue<<<512, 256, 0, stream>>>(Wi, Wc, bc, WiT, W1T, W2T, bcp, deg,
                                      counts);
  k_deg<<<NB_E, 256, 0, stream>>>(ei, ea, deg, counts);
  k_scan<<<1, 1024, 0, stream>>>(counts, deg, dinv, row_ptr, cursor);
  k_fill<<<NB_E, 256, 0, stream>>>(ei, ea, dinv, cursor, csr_src, csr_w);

  k_agg_init<<<NB_AGG, 256, 0, stream>>>(h, c, (unsigned int*)AhAc, dinv,
                                         row_ptr, csr_src, csr_w);
  // states = elu([Ah|Ac]@Wi + bi) -> hbf, c_cur
  k_gemm<0, 256, 256><<<dim3(MB, 2), 256, 0, stream>>>(
      AhAc, WiT, bi, nullptr, c_cur, hbf, nullptr);
  // Kbuf = Ah@W1 + bcp (gate-interleaved), A = AhAc cols 0..127
  k_gemm<1, 128, 256><<<dim3(MB, 4), 256, 0, stream>>>(
      AhAc, W1T, bcp, nullptr, nullptr, nullptr, Kbuf);

  for (int t = 0; t < SEQ; ++t) {
    k_agg_step<<<NB_AGG, 256, 0, stream>>>((unsigned int*)hbf,
                                           (unsigned int*)Aht, dinv, row_ptr,
                                           csr_src, csr_w);
    k_gemm<2, 128, 128><<<dim3(MB, 4), 256, 0, stream>>>(
        Aht, W2T, nullptr, Kbuf, c_cur, hbf, out + (size_t)t * N_NODES * 128);
  }
}